// Round 2
// baseline (10981.379 us; speedup 1.0000x reference)
//
#include <hip/hip_runtime.h>
#include <cstddef>

// ---------------------------------------------------------------------------
// DSSMReverse forward, fp32 correctness-first, ws_size-adaptive chunking.
// B=1024, H=W=20 (400 px), E=8.
// ---------------------------------------------------------------------------

struct ConvArgs {
  const float* in0[3];
  const float* in1[3];   // if non-null: input = in0 - in1 (fused diff)
  const float* w[3];
  const float* bias[3];
  float* out[3];
};

struct GemmArgs {
  const float* X[3];   // [M][K] row-major
  const float* W[3];   // [N][K] row-major (we compute X @ W^T)
  const float* B[3];   // bias [N] or nullptr
  float* Y[3];         // [M][N]
  int K;
  int N;
  int relu;
  const float* scale;  // if non-null: multiply by expf(*scale)
};

// --- embedding renorm (max_norm=1) -----------------------------------------
__global__ void renorm_k(const float* __restrict__ emb, float* __restrict__ tbl) {
  int t = threadIdx.x;
  if (t < 14) {
    float s = 0.f;
    for (int e = 0; e < 8; ++e) { float v = emb[t * 8 + e]; s += v * v; }
    float n = sqrtf(s);
    float sc = (n > 1.0f) ? 1.0f / (n + 1e-7f) : 1.0f;
    for (int e = 0; e < 8; ++e) tbl[t * 8 + e] = emb[t * 8 + e] * sc;
  }
}

// --- gather for one chunk: o[b][e][p] = tbl[idx[start+b][p]][e] ------------
__global__ __launch_bounds__(256) void gather_k(
    const int* __restrict__ s, const int* __restrict__ sp,
    const float* __restrict__ tbl,
    float* __restrict__ o_s, float* __restrict__ o_sp,
    int start, int total) {
  int i = blockIdx.x * 256 + threadIdx.x;   // < C*3200
  if (i >= total) return;
  const int* __restrict__ idx = blockIdx.z ? sp : s;
  float* __restrict__ o = blockIdx.z ? o_sp : o_s;
  int p = i % 400;
  int e = (i / 400) & 7;
  int b = i / 3200;
  o[i] = tbl[idx[(size_t)(start + b) * 400 + p] * 8 + e];
}

// --- 3x3 SAME conv + bias + relu, NCHW, one image per block.x --------------
// block: 256 threads = 4 waves; thread handles 8 cout x 7 pixel positions.
// grid: (C, COUT/32, nz)
template <int CIN, int COUT, int CHUNK>
__global__ __launch_bounds__(256) void conv3x3_relu_k(ConvArgs args) {
  const int b = blockIdx.x;
  const int coT = blockIdx.y;
  const int z = blockIdx.z;
  const float* __restrict__ in0 = args.in0[z];
  const float* __restrict__ in1 = args.in1[z];
  const float* __restrict__ wgt = args.w[z];
  const float* __restrict__ bias = args.bias[z];
  float* __restrict__ out = args.out[z];

  __shared__ float in_lds[CHUNK * 484];       // [CHUNK][22][22] halo-padded
  __shared__ float w_lds[32 * CHUNK * 9];     // [32 cout][CHUNK][9]

  const int tid = threadIdx.x;
  const int p64 = tid & 63;
  const int c4 = tid >> 6;                    // wave id 0..3
  const int cobase = coT * 32 + c4 * 8;

  float acc[8][7];
#pragma unroll
  for (int i = 0; i < 8; ++i)
#pragma unroll
    for (int j = 0; j < 7; ++j) acc[i][j] = 0.f;

  int ph[7], pw[7];
#pragma unroll
  for (int j = 0; j < 7; ++j) {
    int p = p64 + 64 * j;
    if (p > 399) p = 0;                       // clamped; store is masked
    ph[j] = p / 20;
    pw[j] = p % 20;
  }

  for (int cc = 0; cc < CIN; cc += CHUNK) {
    __syncthreads();
    // stage input chunk with zero halo (optionally fused subtraction)
    for (int l = tid; l < CHUNK * 484; l += 256) {
      int c = l / 484;
      int r = l - c * 484;
      int hh = r / 22 - 1;
      int ww = r % 22 - 1;
      float v = 0.f;
      if (hh >= 0 && hh < 20 && ww >= 0 && ww < 20) {
        size_t gi = ((size_t)b * CIN + cc + c) * 400 + hh * 20 + ww;
        v = in0[gi];
        if (in1) v -= in1[gi];
      }
      in_lds[l] = v;
    }
    // stage weights for this (cout-tile, cin-chunk)
    for (int l = tid; l < 32 * CHUNK * 9; l += 256) {
      int co = l / (CHUNK * 9);
      int rest = l - co * CHUNK * 9;          // = c*9 + k
      w_lds[l] = wgt[((size_t)(coT * 32 + co) * CIN + cc) * 9 + rest];
    }
    __syncthreads();

#pragma unroll 4
    for (int cin = 0; cin < CHUNK; ++cin) {
      const float* ib = &in_lds[cin * 484];
      float i9[7][9];
#pragma unroll
      for (int j = 0; j < 7; ++j) {
        const float* p0 = ib + ph[j] * 22 + pw[j];
#pragma unroll
        for (int r = 0; r < 3; ++r) {
          i9[j][r * 3 + 0] = p0[r * 22 + 0];
          i9[j][r * 3 + 1] = p0[r * 22 + 1];
          i9[j][r * 3 + 2] = p0[r * 22 + 2];
        }
      }
      const float* wb = &w_lds[(c4 * 8) * CHUNK * 9 + cin * 9];
#pragma unroll
      for (int co = 0; co < 8; ++co) {
        float wr[9];
#pragma unroll
        for (int k = 0; k < 9; ++k) wr[k] = wb[co * CHUNK * 9 + k];
#pragma unroll
        for (int j = 0; j < 7; ++j) {
          float a = acc[co][j];
#pragma unroll
          for (int k = 0; k < 9; ++k) a = fmaf(i9[j][k], wr[k], a);
          acc[co][j] = a;
        }
      }
    }
  }

#pragma unroll
  for (int co = 0; co < 8; ++co) {
    float bv = bias[cobase + co];
#pragma unroll
    for (int j = 0; j < 7; ++j) {
      int p = p64 + 64 * j;
      if (p < 400) {
        float v = fmaxf(acc[co][j] + bv, 0.f);
        out[((size_t)b * COUT + cobase + co) * 400 + p] = v;
      }
    }
  }
}

// --- full-K GEMM: Y = f(X @ W^T + bias) * alpha; 64x64 tile, 4x4 micro -----
__global__ __launch_bounds__(256) void gemm_xwT_k(GemmArgs g) {
  const int z = blockIdx.z;
  const float* __restrict__ X = g.X[z];
  const float* __restrict__ W = g.W[z];
  const float* __restrict__ Bi = g.B[z];
  float* __restrict__ Y = g.Y[z];
  const int K = g.K, N = g.N;
  const int m0 = blockIdx.x * 64, n0 = blockIdx.y * 64;

  __shared__ float Xs[16][68];
  __shared__ float Ws[16][68];

  const int tid = threadIdx.x;
  const int tm = tid & 15, tn = tid >> 4;
  const int lr = tid >> 2, lc = (tid & 3) << 2;

  float acc[4][4];
#pragma unroll
  for (int i = 0; i < 4; ++i)
#pragma unroll
    for (int j = 0; j < 4; ++j) acc[i][j] = 0.f;

  const float* xg = X + (size_t)(m0 + lr) * K + lc;
  const float* wg = W + (size_t)(n0 + lr) * K + lc;

  for (int k0 = 0; k0 < K; k0 += 16) {
    float4 xv = *(const float4*)(xg + k0);
    float4 wv = *(const float4*)(wg + k0);
    __syncthreads();
    Xs[lc + 0][lr] = xv.x; Xs[lc + 1][lr] = xv.y;
    Xs[lc + 2][lr] = xv.z; Xs[lc + 3][lr] = xv.w;
    Ws[lc + 0][lr] = wv.x; Ws[lc + 1][lr] = wv.y;
    Ws[lc + 2][lr] = wv.z; Ws[lc + 3][lr] = wv.w;
    __syncthreads();
#pragma unroll
    for (int k = 0; k < 16; ++k) {
      float4 a = *(const float4*)(&Xs[k][tm << 2]);
      float4 bv = *(const float4*)(&Ws[k][tn << 2]);
      acc[0][0] = fmaf(a.x, bv.x, acc[0][0]); acc[0][1] = fmaf(a.x, bv.y, acc[0][1]);
      acc[0][2] = fmaf(a.x, bv.z, acc[0][2]); acc[0][3] = fmaf(a.x, bv.w, acc[0][3]);
      acc[1][0] = fmaf(a.y, bv.x, acc[1][0]); acc[1][1] = fmaf(a.y, bv.y, acc[1][1]);
      acc[1][2] = fmaf(a.y, bv.z, acc[1][2]); acc[1][3] = fmaf(a.y, bv.w, acc[1][3]);
      acc[2][0] = fmaf(a.z, bv.x, acc[2][0]); acc[2][1] = fmaf(a.z, bv.y, acc[2][1]);
      acc[2][2] = fmaf(a.z, bv.z, acc[2][2]); acc[2][3] = fmaf(a.z, bv.w, acc[2][3]);
      acc[3][0] = fmaf(a.w, bv.x, acc[3][0]); acc[3][1] = fmaf(a.w, bv.y, acc[3][1]);
      acc[3][2] = fmaf(a.w, bv.z, acc[3][2]); acc[3][3] = fmaf(a.w, bv.w, acc[3][3]);
    }
  }

  float alpha = 1.0f;
  if (g.scale) alpha = expf(g.scale[0]);
#pragma unroll
  for (int i = 0; i < 4; ++i) {
    size_t row = (size_t)(m0 + tm * 4 + i) * N + n0;
#pragma unroll
    for (int j = 0; j < 4; ++j) {
      float v = acc[i][j];
      if (Bi) v += Bi[n0 + tn * 4 + j];
      if (g.relu) v = fmaxf(v, 0.f);
      Y[row + tn * 4 + j] = v * alpha;
    }
  }
}

// --- split-K GEMM: Y += X @ W^T over K slice (atomicAdd); Y pre-init=bias --
// grid: (M/64, N/64, KS), block 256
__global__ __launch_bounds__(256) void gemm_splitk_k(
    const float* __restrict__ X, const float* __restrict__ W,
    float* __restrict__ Y, int K, int N, int klen) {
  const int m0 = blockIdx.x * 64, n0 = blockIdx.y * 64;
  const int kb = blockIdx.z * klen;

  __shared__ float Xs[16][68];
  __shared__ float Ws[16][68];

  const int tid = threadIdx.x;
  const int tm = tid & 15, tn = tid >> 4;
  const int lr = tid >> 2, lc = (tid & 3) << 2;

  float acc[4][4];
#pragma unroll
  for (int i = 0; i < 4; ++i)
#pragma unroll
    for (int j = 0; j < 4; ++j) acc[i][j] = 0.f;

  const float* xg = X + (size_t)(m0 + lr) * K + lc + kb;
  const float* wg = W + (size_t)(n0 + lr) * K + lc + kb;

  for (int k0 = 0; k0 < klen; k0 += 16) {
    float4 xv = *(const float4*)(xg + k0);
    float4 wv = *(const float4*)(wg + k0);
    __syncthreads();
    Xs[lc + 0][lr] = xv.x; Xs[lc + 1][lr] = xv.y;
    Xs[lc + 2][lr] = xv.z; Xs[lc + 3][lr] = xv.w;
    Ws[lc + 0][lr] = wv.x; Ws[lc + 1][lr] = wv.y;
    Ws[lc + 2][lr] = wv.z; Ws[lc + 3][lr] = wv.w;
    __syncthreads();
#pragma unroll
    for (int k = 0; k < 16; ++k) {
      float4 a = *(const float4*)(&Xs[k][tm << 2]);
      float4 bv = *(const float4*)(&Ws[k][tn << 2]);
      acc[0][0] = fmaf(a.x, bv.x, acc[0][0]); acc[0][1] = fmaf(a.x, bv.y, acc[0][1]);
      acc[0][2] = fmaf(a.x, bv.z, acc[0][2]); acc[0][3] = fmaf(a.x, bv.w, acc[0][3]);
      acc[1][0] = fmaf(a.y, bv.x, acc[1][0]); acc[1][1] = fmaf(a.y, bv.y, acc[1][1]);
      acc[1][2] = fmaf(a.y, bv.z, acc[1][2]); acc[1][3] = fmaf(a.y, bv.w, acc[1][3]);
      acc[2][0] = fmaf(a.z, bv.x, acc[2][0]); acc[2][1] = fmaf(a.z, bv.y, acc[2][1]);
      acc[2][2] = fmaf(a.z, bv.z, acc[2][2]); acc[2][3] = fmaf(a.z, bv.w, acc[2][3]);
      acc[3][0] = fmaf(a.w, bv.x, acc[3][0]); acc[3][1] = fmaf(a.w, bv.y, acc[3][1]);
      acc[3][2] = fmaf(a.w, bv.z, acc[3][2]); acc[3][3] = fmaf(a.w, bv.w, acc[3][3]);
    }
  }

#pragma unroll
  for (int i = 0; i < 4; ++i) {
    size_t row = (size_t)(m0 + tm * 4 + i) * N + n0;
#pragma unroll
    for (int j = 0; j < 4; ++j)
      atomicAdd(&Y[row + tn * 4 + j], acc[i][j]);
  }
}

// --- init lin buffers with bias (for split-K accumulation) -----------------
__global__ __launch_bounds__(256) void initlin_k(
    float* l0, float* l1, float* l2,
    const float* b0, const float* b1, const float* b2) {
  int i = blockIdx.x * 256 + threadIdx.x;     // < 1024*512
  float* Y = blockIdx.y == 0 ? l0 : (blockIdx.y == 1 ? l1 : l2);
  const float* B = blockIdx.y == 0 ? b0 : (blockIdx.y == 1 ? b1 : b2);
  Y[i] = B[i & 511];
}

// --- quantize: argmax_l dist(diff[b], z[l]) over 64 codes; hq = s_int + z[best]
__global__ __launch_bounds__(256) void quantize_k(
    const float* __restrict__ diff_int, const float* __restrict__ s_int,
    const float* __restrict__ z_vec, float* __restrict__ hq) {
  const int wv = threadIdx.x >> 6, lane = threadIdx.x & 63;
  const int row = blockIdx.x * 4 + wv;      // 0..1023
  const float* d = diff_int + (size_t)row * 512;
  const float* zr = z_vec + (size_t)lane * 512;
  float dot = 0.f, zz = 0.f;
  for (int k = 0; k < 512; k += 4) {
    float4 dv = *(const float4*)(d + k);
    float4 zv = *(const float4*)(zr + k);
    dot = fmaf(dv.x, zv.x, dot); dot = fmaf(dv.y, zv.y, dot);
    dot = fmaf(dv.z, zv.z, dot); dot = fmaf(dv.w, zv.w, dot);
    zz = fmaf(zv.x, zv.x, zz); zz = fmaf(zv.y, zv.y, zz);
    zz = fmaf(zv.z, zv.z, zz); zz = fmaf(zv.w, zv.w, zz);
  }
  float gval = zz - 2.0f * dot;             // dist^2 minus const ||diff||^2
  int best = lane;
  float bg = gval;
#pragma unroll
  for (int off = 32; off; off >>= 1) {
    float og = __shfl_xor(bg, off);
    int ob = __shfl_xor(best, off);
    if (og > bg || (og == bg && ob < best)) { bg = og; best = ob; }
  }
  const float* zb = z_vec + (size_t)best * 512;
  const float* si = s_int + (size_t)row * 512;
  float* o = hq + (size_t)row * 512;
  for (int k = lane; k < 512; k += 64) o[k] = si[k] + zb[k];
}

// --- row normalize: y = x / (||x|| + 1e-4); one wave per 512-row -----------
__global__ __launch_bounds__(256) void normalize_k(
    const float* __restrict__ v0, const float* __restrict__ v1,
    float* __restrict__ o0, float* __restrict__ o1) {
  const int wv = threadIdx.x >> 6, lane = threadIdx.x & 63;
  const int row = blockIdx.x * 4 + wv;
  const float* x = (blockIdx.y ? v1 : v0) + (size_t)row * 512;
  float* o = (blockIdx.y ? o1 : o0) + (size_t)row * 512;
  float vals[8];
  float ss = 0.f;
#pragma unroll
  for (int k = 0; k < 8; ++k) {
    vals[k] = x[lane + 64 * k];
    ss = fmaf(vals[k], vals[k], ss);
  }
#pragma unroll
  for (int off = 32; off; off >>= 1) ss += __shfl_xor(ss, off);
  float inv = 1.0f / (sqrtf(ss) + 1e-4f);
#pragma unroll
  for (int k = 0; k < 8; ++k) o[lane + 64 * k] = vals[k] * inv;
}

// ---------------------------------------------------------------------------
extern "C" void kernel_launch(void* const* d_in, const int* in_sizes, int n_in,
                              void* d_out, int out_size, void* d_ws, size_t ws_size,
                              hipStream_t stream) {
  (void)in_sizes; (void)n_in; (void)out_size;
  const int* s  = (const int*)d_in[0];
  const int* sp = (const int*)d_in[1];
  const float* emb   = (const float*)d_in[3];
  const float* ec0_w = (const float*)d_in[4];
  const float* ec0_b = (const float*)d_in[5];
  const float* ec1_w = (const float*)d_in[6];
  const float* ec1_b = (const float*)d_in[7];
  const float* pc0_w[3] = {(const float*)d_in[8],  (const float*)d_in[14], (const float*)d_in[20]};
  const float* pc0_b[3] = {(const float*)d_in[9],  (const float*)d_in[15], (const float*)d_in[21]};
  const float* pc1_w[3] = {(const float*)d_in[10], (const float*)d_in[16], (const float*)d_in[22]};
  const float* pc1_b[3] = {(const float*)d_in[11], (const float*)d_in[17], (const float*)d_in[23]};
  const float* pl_w[3]  = {(const float*)d_in[12], (const float*)d_in[18], (const float*)d_in[24]};
  const float* pl_b[3]  = {(const float*)d_in[13], (const float*)d_in[19], (const float*)d_in[25]};
  const float* fc0_w  = (const float*)d_in[26];
  const float* fc0_b  = (const float*)d_in[27];
  const float* fc1_w  = (const float*)d_in[28];
  const float* fc1_b  = (const float*)d_in[29];
  const float* p3f0_w = (const float*)d_in[30];
  const float* p3f0_b = (const float*)d_in[31];
  const float* p3f1_w = (const float*)d_in[32];
  const float* p3f1_b = (const float*)d_in[33];
  const float* z_vec  = (const float*)d_in[34];
  const float* scale  = (const float*)d_in[35];
  float* outp = (float*)d_out;

  // ---- pick chunk size C: largest in {1024..64} whose layout fits ws_size --
  // floats needed: 256 (tbl) + 10*524288 (smalls) + C*(3*25600 + 51200)
  const size_t SMALLS = 10u * 524288u;
  int C = 1024;
  while (C > 64) {
    size_t need = (256 + SMALLS + (size_t)C * 128000) * 4;
    if (need <= ws_size) break;
    C >>= 1;
  }
  const int NCHUNK = 1024 / C;

  // ---- workspace layout (floats) ----
  float* ws = (float*)d_ws;
  float* tbl_n = ws;                          // 256
  float* lin0 = ws + 256;                     // s_int       [1024][512]
  float* lin1 = lin0 + 524288;                // diff_int
  float* lin2 = lin1 + 524288;                // h3
  float* hq   = lin2 + 524288;
  float* u0   = hq + 524288;
  float* u1   = u0 + 524288;
  float* v0   = u1 + 524288;
  float* v1   = v0 + 524288;
  float* so   = v1 + 524288;
  float* spo  = so + 524288;
  float* s_emb  = spo + 524288;               // [C][64][400]
  float* sp_emb = s_emb + (size_t)C * 25600;
  float* t0     = sp_emb + (size_t)C * 25600; // [C][64][400]
  float* t1     = t0 + (size_t)C * 25600;     // [C][128][400]
  // aliases inside t0∪t1 (dead at gather/ec time):
  float* x8_s   = t0;                         // [C][8][400]
  float* x8_sp  = x8_s + (size_t)C * 3200;
  float* a32_s  = x8_sp + (size_t)C * 3200;   // [C][32][400]
  float* a32_sp = a32_s + (size_t)C * 12800;

  // split-K factor so the big GEMM has ~256 blocks per launch
  int KS = 256 / ((C / 64) * 8);
  if (KS < 1) KS = 1;
  if (KS > 32) KS = 32;
  const int KLEN = 51200 / KS;

  // 1. embedding renorm
  renorm_k<<<1, 64, 0, stream>>>(emb, tbl_n);
  // 2. init lin accumulators with bias
  initlin_k<<<dim3(2048, 3), 256, 0, stream>>>(lin0, lin1, lin2,
                                               pl_b[0], pl_b[1], pl_b[2]);

  for (int ch = 0; ch < NCHUNK; ++ch) {
    const int start = ch * C;
    // 3. gather to [C,8,20,20] for s and s'
    gather_k<<<dim3((C * 3200 + 255) / 256, 1, 2), 256, 0, stream>>>(
        s, sp, tbl_n, x8_s, x8_sp, start, C * 3200);
    // 4. ec0: 8->32 (both states batched in z)
    {
      ConvArgs a{};
      a.in0[0] = x8_s;  a.w[0] = ec0_w; a.bias[0] = ec0_b; a.out[0] = a32_s;
      a.in0[1] = x8_sp; a.w[1] = ec0_w; a.bias[1] = ec0_b; a.out[1] = a32_sp;
      conv3x3_relu_k<8, 32, 8><<<dim3(C, 1, 2), 256, 0, stream>>>(a);
    }
    // 5. ec1: 32->64
    {
      ConvArgs a{};
      a.in0[0] = a32_s;  a.w[0] = ec1_w; a.bias[0] = ec1_b; a.out[0] = s_emb;
      a.in0[1] = a32_sp; a.w[1] = ec1_w; a.bias[1] = ec1_b; a.out[1] = sp_emb;
      conv3x3_relu_k<32, 64, 16><<<dim3(C, 2, 2), 256, 0, stream>>>(a);
    }
    // 6. three phi paths, sequential (t0/t1 reused)
    for (int p = 0; p < 3; ++p) {
      {
        ConvArgs a{};
        a.in0[0] = (p == 0) ? s_emb : sp_emb;
        a.in1[0] = (p == 1) ? s_emb : nullptr;   // path 1: sp_emb - s_emb
        a.w[0] = pc0_w[p]; a.bias[0] = pc0_b[p]; a.out[0] = t0;
        conv3x3_relu_k<64, 64, 16><<<dim3(C, 2, 1), 256, 0, stream>>>(a);
      }
      {
        ConvArgs a{};
        a.in0[0] = t0; a.w[0] = pc1_w[p]; a.bias[0] = pc1_b[p]; a.out[0] = t1;
        conv3x3_relu_k<64, 128, 16><<<dim3(C, 4, 1), 256, 0, stream>>>(a);
      }
      float* lin = (p == 0) ? lin0 : (p == 1) ? lin1 : lin2;
      gemm_splitk_k<<<dim3(C / 64, 8, KS), 256, 0, stream>>>(
          t1, pl_w[p], lin + (size_t)start * 512, 51200, 512, KLEN);
    }
  }

  // 7. quantize + add codebook row
  quantize_k<<<256, 256, 0, stream>>>(lin1, lin0, z_vec, hq);
  // 8. fc0 / p3f0 with relu
  {
    GemmArgs g{};
    g.X[0] = hq;   g.W[0] = fc0_w;  g.B[0] = fc0_b;  g.Y[0] = u0;
    g.X[1] = lin2; g.W[1] = p3f0_w; g.B[1] = p3f0_b; g.Y[1] = u1;
    g.K = 512; g.N = 512; g.relu = 1; g.scale = nullptr;
    gemm_xwT_k<<<dim3(16, 8, 2), 256, 0, stream>>>(g);
  }
  // 9. fc1 / p3f1 (no relu)
  {
    GemmArgs g{};
    g.X[0] = u0; g.W[0] = fc1_w;  g.B[0] = fc1_b;  g.Y[0] = v0;
    g.X[1] = u1; g.W[1] = p3f1_w; g.B[1] = p3f1_b; g.Y[1] = v1;
    g.K = 512; g.N = 512; g.relu = 0; g.scale = nullptr;
    gemm_xwT_k<<<dim3(16, 8, 2), 256, 0, stream>>>(g);
  }
  // 10. normalize both
  normalize_k<<<dim3(256, 2), 256, 0, stream>>>(v0, v1, so, spo);
  // 11. ipm = exp(scale) * s_out @ sp_out^T
  {
    GemmArgs g{};
    g.X[0] = so; g.W[0] = spo; g.B[0] = nullptr; g.Y[0] = outp;
    g.K = 512; g.N = 1024; g.relu = 0; g.scale = scale;
    gemm_xwT_k<<<dim3(16, 16, 1), 256, 0, stream>>>(g);
  }
}

// Round 3
// 1884.070 us; speedup vs baseline: 5.8285x; 5.8285x over previous
//
#include <hip/hip_runtime.h>
#include <cstddef>

// ---------------------------------------------------------------------------
// DSSMReverse forward. fp16 MFMA convs + big linear; fp32 tail.
// B=1024, H=W=20 (400 px), E=8.
// ---------------------------------------------------------------------------

typedef _Float16 f16;
typedef _Float16 f16x8 __attribute__((ext_vector_type(8)));
typedef _Float16 f16x4 __attribute__((ext_vector_type(4)));
typedef float f32x4 __attribute__((ext_vector_type(4)));

struct ConvArgs {
  const f16* in0[3];
  const f16* in1[3];    // if non-null: input = in0 - in1 (fused diff)
  const f16* wr[3];     // reordered fp16 weights [co][tap*CIN+cin] (KPAD k-dim)
  const float* bias[3];
  f16* out[3];
};

struct WROrd {
  const float* w[3];
  f16* o[3];
  int COUT, CIN, KPAD;
};

struct GemmArgs {
  const float* X[3];
  const float* W[3];
  const float* B[3];
  float* Y[3];
  int K, N, relu;
  const float* scale;
};

// --- embedding renorm (max_norm=1), emits fp16 table -----------------------
__global__ void renorm_k(const float* __restrict__ emb, f16* __restrict__ tbl) {
  int t = threadIdx.x;
  if (t < 14) {
    float s = 0.f;
    for (int e = 0; e < 8; ++e) { float v = emb[t * 8 + e]; s += v * v; }
    float n = sqrtf(s);
    float sc = (n > 1.0f) ? 1.0f / (n + 1e-7f) : 1.0f;
    for (int e = 0; e < 8; ++e) tbl[t * 8 + e] = (f16)(emb[t * 8 + e] * sc);
  }
}

// --- weight reorder: o[z][co*KPAD + tap*CIN + cin] = w[z][co][cin][tap] ----
__global__ __launch_bounds__(256) void wreorder_k(WROrd a) {
  int i = blockIdx.x * 256 + threadIdx.x;
  int z = blockIdx.z;
  if (i >= a.COUT * a.KPAD) return;
  int co = i / a.KPAD, k = i % a.KPAD;
  int tap = k / a.CIN, cin = k % a.CIN;
  float v = (tap < 9) ? a.w[z][((size_t)co * a.CIN + cin) * 9 + tap] : 0.f;
  a.o[z][i] = (f16)v;
}

// --- gather NHWC fp16: o[b][p][e] = tbl[idx[b][p]][e] ----------------------
__global__ __launch_bounds__(256) void gather_k(
    const int* __restrict__ s, const int* __restrict__ sp,
    const f16* __restrict__ tbl, f16* __restrict__ o_s, f16* __restrict__ o_sp,
    int start) {
  int i = blockIdx.x * 256 + threadIdx.x;   // < C*400
  int bp = start * 400 + i;
  uint4 rs = ((const uint4*)tbl)[s[bp]];
  uint4 rp = ((const uint4*)tbl)[sp[bp]];
  ((uint4*)o_s)[i] = rs;
  ((uint4*)o_sp)[i] = rp;
}

// --- MFMA 3x3 SAME conv + bias + relu, NHWC fp16 in --------------------------
// grid (C, COUT/COT, nz). block 256 = 4 waves. wave: 7 Mtiles x NT Ntiles.
template <int CIN, int CINC, int COT, bool NCHW_OUT, int OC, int KPAD>
__global__ __launch_bounds__(256) void conv_mfma_k(ConvArgs args) {
  constexpr int TPS = 32 / CINC;               // taps per 32-K mfma step
  constexpr int KSTEPS = (9 + TPS - 1) / TPS;  // 9 (cinc32) / 5 (cinc16) / 3 (cinc8)
  constexpr int WROW = KSTEPS * 32 + 8;
  constexpr int CS = (CINC == 32) ? 40 : (CINC == 16 ? 24 : 8);
  constexpr int NT = COT / 16;
  constexpr int NCH = CIN / CINC;
  constexpr int GPP = CINC / 8;                // 8-elem groups per pixel

  const int b = blockIdx.x;
  const int cobase = blockIdx.y * COT;
  const int z = blockIdx.z;
  const f16* __restrict__ in0 = args.in0[z];
  const f16* __restrict__ in1 = args.in1[z];
  const f16* __restrict__ wr = args.wr[z];
  const float* __restrict__ bias = args.bias[z];
  f16* __restrict__ out = args.out[z];

  __shared__ f16 in_lds[484 * CS];
  __shared__ f16 w_lds[COT * WROW];

  const int tid = threadIdx.x;
  const int lane = tid & 63;
  const int wv = tid >> 6;
  const int l15 = lane & 15;
  const int quad = lane >> 4;

  // per-wave Mtiles: mt = wv + 4*i (mt>=25 is padding, stores masked)
  int qbase[7];
#pragma unroll
  for (int i = 0; i < 7; ++i) {
    int mt = wv + 4 * i;
    int p = mt * 16 + l15;
    if (p > 399) p = 399;
    qbase[i] = (p / 20 + 1) * 22 + (p % 20 + 1);
  }

  f32x4 acc[7][NT];
#pragma unroll
  for (int i = 0; i < 7; ++i)
#pragma unroll
    for (int n = 0; n < NT; ++n) acc[i][n] = (f32x4){0.f, 0.f, 0.f, 0.f};

  for (int cc = 0; cc < NCH; ++cc) {
    __syncthreads();
    // ---- stage input chunk: [484 padded px][CINC] fp16, zero halo ----
    for (int l = tid; l < 484 * GPP; l += 256) {
      int pp = l / GPP, g = l % GPP;
      int hp = pp / 22, wp = pp % 22;
      f16x8 v = {0, 0, 0, 0, 0, 0, 0, 0};
      if (hp >= 1 && hp <= 20 && wp >= 1 && wp <= 20) {
        int p = (hp - 1) * 20 + (wp - 1);
        size_t gi = ((size_t)b * 400 + p) * CIN + cc * CINC + g * 8;
        v = *(const f16x8*)(in0 + gi);
        if (in1) v = v - *(const f16x8*)(in1 + gi);
      }
      *(f16x8*)(&in_lds[pp * CS + g * 8]) = v;
    }
    // ---- stage weights for this cin-chunk (b128 copies from wr) ----
    for (int l = tid; l < COT * KSTEPS * 4; l += 256) {
      int co = l / (KSTEPS * 4);
      int rem = l % (KSTEPS * 4);
      int s2 = rem >> 2, g = rem & 3;
      int tap, src;
      if (GPP == 4)      { tap = s2;               src = s2 * CIN + cc * 32 + g * 8; }
      else if (GPP == 2) { tap = s2 * 2 + (g >> 1); src = tap * CIN + cc * 16 + (g & 1) * 8; }
      else               { tap = s2 * 4 + g;        src = s2 * 32 + g * 8; }
      f16x8 wv8 = {0, 0, 0, 0, 0, 0, 0, 0};
      if (GPP == 1 || tap < 9)   // ec0's wr is zero-padded to KPAD already
        wv8 = *(const f16x8*)(&wr[(size_t)(cobase + co) * KPAD + src]);
      *(f16x8*)(&w_lds[co * WROW + s2 * 32 + g * 8]) = wv8;
    }
    __syncthreads();

    // ---- MFMA over ksteps ----
#pragma unroll
    for (int s = 0; s < KSTEPS; ++s) {
      f16x8 bf[NT];
#pragma unroll
      for (int n = 0; n < NT; ++n)
        bf[n] = *(const f16x8*)(&w_lds[(n * 16 + l15) * WROW + s * 32 + quad * 8]);
      int tap = (GPP == 4) ? s : (GPP == 2 ? s * 2 + (quad >> 1) : s * 4 + quad);
      if (tap > 8) tap = 8;  // padded tap: B=0, A value irrelevant
      int toff = (tap / 3 - 1) * 22 + (tap % 3 - 1);
      int coff = (GPP == 4) ? quad * 8 : (GPP == 2 ? (quad & 1) * 8 : 0);
#pragma unroll
      for (int i = 0; i < 7; ++i) {
        f16x8 af = *(const f16x8*)(&in_lds[(qbase[i] + toff) * CS + coff]);
#pragma unroll
        for (int n = 0; n < NT; ++n)
          acc[i][n] = __builtin_amdgcn_mfma_f32_16x16x32_f16(af, bf[n], acc[i][n], 0, 0, 0);
      }
    }
  }

  // ---- epilogue: bias + relu + fp16 store ----
#pragma unroll
  for (int i = 0; i < 7; ++i) {
    int mt = wv + 4 * i;
    if (mt >= 25) continue;
#pragma unroll
    for (int n = 0; n < NT; ++n) {
      int co = cobase + n * 16 + l15;
      float bv = bias[co];
      if (NCHW_OUT) {
        f16x4 pk;
#pragma unroll
        for (int r = 0; r < 4; ++r)
          pk[r] = (f16)fmaxf(acc[i][n][r] + bv, 0.f);
        *(f16x4*)(&out[(size_t)b * (400 * OC) + (size_t)co * 400 + mt * 16 + quad * 4]) = pk;
      } else {
#pragma unroll
        for (int r = 0; r < 4; ++r) {
          int pix = mt * 16 + quad * 4 + r;
          out[((size_t)b * 400 + pix) * OC + co] =
              (f16)fmaxf(acc[i][n][r] + bv, 0.f);
        }
      }
    }
  }
}

// --- big linear: lin += X(fp16,NCHW-flat) @ W(fp32,cast-in-staging)^T ------
// grid (C/128, 4, 20). K=51200, kslice=2560. atomics into bias-pre-init Y.
__global__ __launch_bounds__(256) void gemm_big_k(
    const f16* __restrict__ X, const float* __restrict__ W,
    float* __restrict__ Y) {
  const int m0 = blockIdx.x * 128, n0 = blockIdx.y * 128;
  const int kb = blockIdx.z * 2560;
  __shared__ f16 Xs[128 * 40];
  __shared__ f16 Ws[128 * 40];

  const int tid = threadIdx.x;
  const int lane = tid & 63, wv = tid >> 6;
  const int l15 = lane & 15, quad = lane >> 4;
  const int wm = (wv >> 1) * 64, wn = (wv & 1) * 64;
  const int srow = tid >> 1, shalf = tid & 1;

  f32x4 acc[4][4];
#pragma unroll
  for (int i = 0; i < 4; ++i)
#pragma unroll
    for (int j = 0; j < 4; ++j) acc[i][j] = (f32x4){0.f, 0.f, 0.f, 0.f};

  const f16* xg = X + (size_t)(m0 + srow) * 51200 + kb + shalf * 16;
  const float* wg = W + (size_t)(n0 + srow) * 51200 + kb + shalf * 16;

  for (int k0 = 0; k0 < 2560; k0 += 32) {
    f16x8 x0 = *(const f16x8*)(xg + k0);
    f16x8 x1 = *(const f16x8*)(xg + k0 + 8);
    float4 w0 = *(const float4*)(wg + k0);
    float4 w1 = *(const float4*)(wg + k0 + 4);
    float4 w2 = *(const float4*)(wg + k0 + 8);
    float4 w3 = *(const float4*)(wg + k0 + 12);
    __syncthreads();
    *(f16x8*)(&Xs[srow * 40 + shalf * 16]) = x0;
    *(f16x8*)(&Xs[srow * 40 + shalf * 16 + 8]) = x1;
    f16x8 wa = {(f16)w0.x, (f16)w0.y, (f16)w0.z, (f16)w0.w,
                (f16)w1.x, (f16)w1.y, (f16)w1.z, (f16)w1.w};
    f16x8 wb = {(f16)w2.x, (f16)w2.y, (f16)w2.z, (f16)w2.w,
                (f16)w3.x, (f16)w3.y, (f16)w3.z, (f16)w3.w};
    *(f16x8*)(&Ws[srow * 40 + shalf * 16]) = wa;
    *(f16x8*)(&Ws[srow * 40 + shalf * 16 + 8]) = wb;
    __syncthreads();
    f16x8 a[4], bfr[4];
#pragma unroll
    for (int t = 0; t < 4; ++t) {
      a[t] = *(const f16x8*)(&Xs[(wm + t * 16 + l15) * 40 + quad * 8]);
      bfr[t] = *(const f16x8*)(&Ws[(wn + t * 16 + l15) * 40 + quad * 8]);
    }
#pragma unroll
    for (int mt = 0; mt < 4; ++mt)
#pragma unroll
      for (int nt = 0; nt < 4; ++nt)
        acc[mt][nt] = __builtin_amdgcn_mfma_f32_16x16x32_f16(a[mt], bfr[nt], acc[mt][nt], 0, 0, 0);
  }

#pragma unroll
  for (int mt = 0; mt < 4; ++mt)
#pragma unroll
    for (int nt = 0; nt < 4; ++nt) {
      int row = m0 + wm + mt * 16 + quad * 4;
      int col = n0 + wn + nt * 16 + l15;
#pragma unroll
      for (int r = 0; r < 4; ++r)
        atomicAdd(&Y[(size_t)(row + r) * 512 + col], acc[mt][nt][r]);
    }
}

// --- init lin buffers with bias --------------------------------------------
__global__ __launch_bounds__(256) void initlin_k(
    float* l0, float* l1, float* l2,
    const float* b0, const float* b1, const float* b2) {
  int i = blockIdx.x * 256 + threadIdx.x;
  float* Y = blockIdx.y == 0 ? l0 : (blockIdx.y == 1 ? l1 : l2);
  const float* B = blockIdx.y == 0 ? b0 : (blockIdx.y == 1 ? b1 : b2);
  Y[i] = B[i & 511];
}

// --- fp32 GEMM for small layers (unchanged from R2) ------------------------
__global__ __launch_bounds__(256) void gemm_xwT_k(GemmArgs g) {
  const int z = blockIdx.z;
  const float* __restrict__ X = g.X[z];
  const float* __restrict__ W = g.W[z];
  const float* __restrict__ Bi = g.B[z];
  float* __restrict__ Y = g.Y[z];
  const int K = g.K, N = g.N;
  const int m0 = blockIdx.x * 64, n0 = blockIdx.y * 64;
  __shared__ float Xs[16][68];
  __shared__ float Ws[16][68];
  const int tid = threadIdx.x;
  const int tm = tid & 15, tn = tid >> 4;
  const int lr = tid >> 2, lc = (tid & 3) << 2;
  float acc[4][4];
#pragma unroll
  for (int i = 0; i < 4; ++i)
#pragma unroll
    for (int j = 0; j < 4; ++j) acc[i][j] = 0.f;
  const float* xg = X + (size_t)(m0 + lr) * K + lc;
  const float* wg = W + (size_t)(n0 + lr) * K + lc;
  for (int k0 = 0; k0 < K; k0 += 16) {
    float4 xv = *(const float4*)(xg + k0);
    float4 wv = *(const float4*)(wg + k0);
    __syncthreads();
    Xs[lc + 0][lr] = xv.x; Xs[lc + 1][lr] = xv.y;
    Xs[lc + 2][lr] = xv.z; Xs[lc + 3][lr] = xv.w;
    Ws[lc + 0][lr] = wv.x; Ws[lc + 1][lr] = wv.y;
    Ws[lc + 2][lr] = wv.z; Ws[lc + 3][lr] = wv.w;
    __syncthreads();
#pragma unroll
    for (int k = 0; k < 16; ++k) {
      float4 a = *(const float4*)(&Xs[k][tm << 2]);
      float4 bv = *(const float4*)(&Ws[k][tn << 2]);
      acc[0][0] = fmaf(a.x, bv.x, acc[0][0]); acc[0][1] = fmaf(a.x, bv.y, acc[0][1]);
      acc[0][2] = fmaf(a.x, bv.z, acc[0][2]); acc[0][3] = fmaf(a.x, bv.w, acc[0][3]);
      acc[1][0] = fmaf(a.y, bv.x, acc[1][0]); acc[1][1] = fmaf(a.y, bv.y, acc[1][1]);
      acc[1][2] = fmaf(a.y, bv.z, acc[1][2]); acc[1][3] = fmaf(a.y, bv.w, acc[1][3]);
      acc[2][0] = fmaf(a.z, bv.x, acc[2][0]); acc[2][1] = fmaf(a.z, bv.y, acc[2][1]);
      acc[2][2] = fmaf(a.z, bv.z, acc[2][2]); acc[2][3] = fmaf(a.z, bv.w, acc[2][3]);
      acc[3][0] = fmaf(a.w, bv.x, acc[3][0]); acc[3][1] = fmaf(a.w, bv.y, acc[3][1]);
      acc[3][2] = fmaf(a.w, bv.z, acc[3][2]); acc[3][3] = fmaf(a.w, bv.w, acc[3][3]);
    }
  }
  float alpha = 1.0f;
  if (g.scale) alpha = expf(g.scale[0]);
#pragma unroll
  for (int i = 0; i < 4; ++i) {
    size_t row = (size_t)(m0 + tm * 4 + i) * N + n0;
#pragma unroll
    for (int j = 0; j < 4; ++j) {
      float v = acc[i][j];
      if (Bi) v += Bi[n0 + tn * 4 + j];
      if (g.relu) v = fmaxf(v, 0.f);
      Y[row + tn * 4 + j] = v * alpha;
    }
  }
}

// --- quantize (fp32): argmax_l dist(diff[b], z[l]); hq = s_int + z[best] ---
__global__ __launch_bounds__(256) void quantize_k(
    const float* __restrict__ diff_int, const float* __restrict__ s_int,
    const float* __restrict__ z_vec, float* __restrict__ hq) {
  const int wv = threadIdx.x >> 6, lane = threadIdx.x & 63;
  const int row = blockIdx.x * 4 + wv;
  const float* d = diff_int + (size_t)row * 512;
  const float* zr = z_vec + (size_t)lane * 512;
  float dot = 0.f, zz = 0.f;
  for (int k = 0; k < 512; k += 4) {
    float4 dv = *(const float4*)(d + k);
    float4 zv = *(const float4*)(zr + k);
    dot = fmaf(dv.x, zv.x, dot); dot = fmaf(dv.y, zv.y, dot);
    dot = fmaf(dv.z, zv.z, dot); dot = fmaf(dv.w, zv.w, dot);
    zz = fmaf(zv.x, zv.x, zz); zz = fmaf(zv.y, zv.y, zz);
    zz = fmaf(zv.z, zv.z, zz); zz = fmaf(zv.w, zv.w, zz);
  }
  float gval = zz - 2.0f * dot;
  int best = lane;
  float bg = gval;
#pragma unroll
  for (int off = 32; off; off >>= 1) {
    float og = __shfl_xor(bg, off);
    int ob = __shfl_xor(best, off);
    if (og > bg || (og == bg && ob < best)) { bg = og; best = ob; }
  }
  const float* zb = z_vec + (size_t)best * 512;
  const float* si = s_int + (size_t)row * 512;
  float* o = hq + (size_t)row * 512;
  for (int k = lane; k < 512; k += 64) o[k] = si[k] + zb[k];
}

// --- row normalize ---------------------------------------------------------
__global__ __launch_bounds__(256) void normalize_k(
    const float* __restrict__ v0, const float* __restrict__ v1,
    float* __restrict__ o0, float* __restrict__ o1) {
  const int wv = threadIdx.x >> 6, lane = threadIdx.x & 63;
  const int row = blockIdx.x * 4 + wv;
  const float* x = (blockIdx.y ? v1 : v0) + (size_t)row * 512;
  float* o = (blockIdx.y ? o1 : o0) + (size_t)row * 512;
  float vals[8];
  float ss = 0.f;
#pragma unroll
  for (int k = 0; k < 8; ++k) {
    vals[k] = x[lane + 64 * k];
    ss = fmaf(vals[k], vals[k], ss);
  }
#pragma unroll
  for (int off = 32; off; off >>= 1) ss += __shfl_xor(ss, off);
  float inv = 1.0f / (sqrtf(ss) + 1e-4f);
#pragma unroll
  for (int k = 0; k < 8; ++k) o[lane + 64 * k] = vals[k] * inv;
}

// ---------------------------------------------------------------------------
extern "C" void kernel_launch(void* const* d_in, const int* in_sizes, int n_in,
                              void* d_out, int out_size, void* d_ws, size_t ws_size,
                              hipStream_t stream) {
  (void)in_sizes; (void)n_in; (void)out_size;
  const int* s  = (const int*)d_in[0];
  const int* sp = (const int*)d_in[1];
  const float* emb   = (const float*)d_in[3];
  const float* ec0_w = (const float*)d_in[4];
  const float* ec0_b = (const float*)d_in[5];
  const float* ec1_w = (const float*)d_in[6];
  const float* ec1_b = (const float*)d_in[7];
  const float* pc0_w[3] = {(const float*)d_in[8],  (const float*)d_in[14], (const float*)d_in[20]};
  const float* pc0_b[3] = {(const float*)d_in[9],  (const float*)d_in[15], (const float*)d_in[21]};
  const float* pc1_w[3] = {(const float*)d_in[10], (const float*)d_in[16], (const float*)d_in[22]};
  const float* pc1_b[3] = {(const float*)d_in[11], (const float*)d_in[17], (const float*)d_in[23]};
  const float* pl_w[3]  = {(const float*)d_in[12], (const float*)d_in[18], (const float*)d_in[24]};
  const float* pl_b[3]  = {(const float*)d_in[13], (const float*)d_in[19], (const float*)d_in[25]};
  const float* fc0_w  = (const float*)d_in[26];
  const float* fc0_b  = (const float*)d_in[27];
  const float* fc1_w  = (const float*)d_in[28];
  const float* fc1_b  = (const float*)d_in[29];
  const float* p3f0_w = (const float*)d_in[30];
  const float* p3f0_b = (const float*)d_in[31];
  const float* p3f1_w = (const float*)d_in[32];
  const float* p3f1_b = (const float*)d_in[33];
  const float* z_vec  = (const float*)d_in[34];
  const float* scale  = (const float*)d_in[35];
  float* outp = (float*)d_out;

  // ---- workspace layout ----
  float* ws = (float*)d_ws;
  float* lin0 = ws;
  float* lin1 = lin0 + 524288;
  float* lin2 = lin1 + 524288;
  float* hq   = lin2 + 524288;
  float* u0   = hq + 524288;
  float* u1   = u0 + 524288;
  float* v0   = u1 + 524288;
  float* v1   = v0 + 524288;
  float* so   = v1 + 524288;
  float* spo  = so + 524288;
  f16* hbase  = (f16*)(ws + 10 * 524288);
  f16* tbl_h   = hbase;                 // 128
  f16* wr_ec0  = hbase + 128;           // 32*96   = 3072
  f16* wr_ec1  = wr_ec0 + 3072;         // 64*288  = 18432
  f16* wr_pc0  = wr_ec1 + 18432;        // 3*64*576 = 110592
  f16* wr_pc1  = wr_pc0 + 110592;       // 3*128*576 = 221184
  f16* chunk0  = wr_pc1 + 221184;

  // pick chunk C (images per pass): bytes = fixed + 256000*C
  const size_t FIXED = (size_t)(10 * 524288) * 4 + (size_t)(128 + 3072 + 18432 + 110592 + 221184) * 2;
  int C = 1024;
  while (C > 128) {
    if (FIXED + (size_t)C * 256000 <= ws_size) break;
    C >>= 1;
  }
  const int NCHUNK = 1024 / C;

  f16* emb_s  = chunk0;                       // [C][400][64]
  f16* emb_sp = emb_s + (size_t)C * 25600;
  f16* t0     = emb_sp + (size_t)C * 25600;   // [C][400][64]
  f16* t1     = t0 + (size_t)C * 25600;       // [C][128][400] NCHW
  // aliases inside t1 (dead until pc1 writes it):
  f16* x8_s   = t1;                           // [C][400][8]
  f16* x8_sp  = x8_s + (size_t)C * 3200;
  f16* a32_s  = x8_sp + (size_t)C * 3200;     // [C][400][32]
  f16* a32_sp = a32_s + (size_t)C * 12800;

  // 1. renorm + weight reorders + lin init
  renorm_k<<<1, 64, 0, stream>>>(emb, tbl_h);
  {
    WROrd a{}; a.w[0] = ec0_w; a.o[0] = wr_ec0; a.COUT = 32; a.CIN = 8; a.KPAD = 96;
    wreorder_k<<<dim3(12, 1, 1), 256, 0, stream>>>(a);
  }
  {
    WROrd a{}; a.w[0] = ec1_w; a.o[0] = wr_ec1; a.COUT = 64; a.CIN = 32; a.KPAD = 288;
    wreorder_k<<<dim3(72, 1, 1), 256, 0, stream>>>(a);
  }
  {
    WROrd a{};
    for (int p = 0; p < 3; ++p) { a.w[p] = pc0_w[p]; a.o[p] = wr_pc0 + (size_t)p * 36864; }
    a.COUT = 64; a.CIN = 64; a.KPAD = 576;
    wreorder_k<<<dim3(144, 1, 3), 256, 0, stream>>>(a);
  }
  {
    WROrd a{};
    for (int p = 0; p < 3; ++p) { a.w[p] = pc1_w[p]; a.o[p] = wr_pc1 + (size_t)p * 73728; }
    a.COUT = 128; a.CIN = 64; a.KPAD = 576;
    wreorder_k<<<dim3(288, 1, 3), 256, 0, stream>>>(a);
  }
  initlin_k<<<dim3(2048, 3), 256, 0, stream>>>(lin0, lin1, lin2,
                                               pl_b[0], pl_b[1], pl_b[2]);

  for (int ch = 0; ch < NCHUNK; ++ch) {
    const int start = ch * C;
    gather_k<<<C * 400 / 256, 256, 0, stream>>>(s, sp, tbl_h, x8_s, x8_sp, start);
    {  // ec0: 8->32, both states
      ConvArgs a{};
      a.in0[0] = x8_s;  a.wr[0] = wr_ec0; a.bias[0] = ec0_b; a.out[0] = a32_s;
      a.in0[1] = x8_sp; a.wr[1] = wr_ec0; a.bias[1] = ec0_b; a.out[1] = a32_sp;
      conv_mfma_k<8, 8, 32, false, 32, 96><<<dim3(C, 1, 2), 256, 0, stream>>>(a);
    }
    {  // ec1: 32->64, both states
      ConvArgs a{};
      a.in0[0] = a32_s;  a.wr[0] = wr_ec1; a.bias[0] = ec1_b; a.out[0] = emb_s;
      a.in0[1] = a32_sp; a.wr[1] = wr_ec1; a.bias[1] = ec1_b; a.out[1] = emb_sp;
      conv_mfma_k<32, 16, 64, false, 64, 288><<<dim3(C, 1, 2), 256, 0, stream>>>(a);
    }
    for (int p = 0; p < 3; ++p) {
      {  // pc0: 64->64 (path1 = sp - s fused)
        ConvArgs a{};
        a.in0[0] = (p == 0) ? emb_s : emb_sp;
        a.in1[0] = (p == 1) ? emb_s : nullptr;
        a.wr[0] = wr_pc0 + (size_t)p * 36864; a.bias[0] = pc0_b[p]; a.out[0] = t0;
        conv_mfma_k<64, 16, 64, false, 64, 576><<<dim3(C, 1, 1), 256, 0, stream>>>(a);
      }
      {  // pc1: 64->128, NCHW fp16 out
        ConvArgs a{};
        a.in0[0] = t0;
        a.wr[0] = wr_pc1 + (size_t)p * 73728; a.bias[0] = pc1_b[p]; a.out[0] = t1;
        conv_mfma_k<64, 16, 64, true, 128, 576><<<dim3(C, 2, 1), 256, 0, stream>>>(a);
      }
      float* lin = (p == 0) ? lin0 : (p == 1) ? lin1 : lin2;
      gemm_big_k<<<dim3(C / 128, 4, 20), 256, 0, stream>>>(
          t1, pl_w[p], lin + (size_t)start * 512);
    }
  }

  // tail (fp32, unchanged)
  quantize_k<<<256, 256, 0, stream>>>(lin1, lin0, z_vec, hq);
  {
    GemmArgs g{};
    g.X[0] = hq;   g.W[0] = fc0_w;  g.B[0] = fc0_b;  g.Y[0] = u0;
    g.X[1] = lin2; g.W[1] = p3f0_w; g.B[1] = p3f0_b; g.Y[1] = u1;
    g.K = 512; g.N = 512; g.relu = 1; g.scale = nullptr;
    gemm_xwT_k<<<dim3(16, 8, 2), 256, 0, stream>>>(g);
  }
  {
    GemmArgs g{};
    g.X[0] = u0; g.W[0] = fc1_w;  g.B[0] = fc1_b;  g.Y[0] = v0;
    g.X[1] = u1; g.W[1] = p3f1_w; g.B[1] = p3f1_b; g.Y[1] = v1;
    g.K = 512; g.N = 512; g.relu = 0; g.scale = nullptr;
    gemm_xwT_k<<<dim3(16, 8, 2), 256, 0, stream>>>(g);
  }
  normalize_k<<<dim3(256, 2), 256, 0, stream>>>(v0, v1, so, spo);
  {
    GemmArgs g{};
    g.X[0] = so; g.W[0] = spo; g.B[0] = nullptr; g.Y[0] = outp;
    g.K = 512; g.N = 1024; g.relu = 0; g.scale = scale;
    gemm_xwT_k<<<dim3(16, 16, 1), 256, 0, stream>>>(g);
  }
}